// Round 3
// baseline (3670.911 us; speedup 1.0000x reference)
//
#include <hip/hip_runtime.h>
#include <hip/hip_bf16.h>
#include <math.h>

#define SEQ   32
#define BATCH 1024
#define NN    19
#define HH    128
#define NB    4            /* batch elements per block */
#define MR    (NB*NN)      /* 76 rows per block */
#define SAS   264          /* A/Z row stride (bf16): 528 B = 16B-aligned, 4-bank shift */
#define H0S   128          /* h0 row stride (bf16) */
#define H1S   132          /* h1 row stride (f32): 528 B, 16B-aligned */
#define UBS   128          /* ub row stride (bf16) */
#define NBLK  (BATCH/NB)   /* 256 blocks, 1 per CU */
#define NT    512          /* 8 waves, 2 per SIMD */

#define OFF_G0 0
#define OFF_C0 122880
#define OFF_G1 184320
#define OFF_C1 380928
#define WTOT   479232      /* total weight elems (bf16) */

/* LDS map (ORDER MATTERS: diffusion B-gathers read "rows" 80..95 of A/Bb,
   which run past the buffer into the NEXT region; those values multiply
   zero Sb columns, so they only need to be finite bf16 — A overruns into
   Bb, Bb overruns into ub (both always finite bf16). Do not reorder.)
   h0  @      0  76*128*2 = 19456
   h1  @  19456  76*132*4 = 40128
   A   @  59584  80*264*2 = 42240   (X / Z2-in-place buffer, ping-pong)
   Bb  @ 101824  80*264*2 = 42240   (Z1 / cand-X buffer, ping-pong)
   ub  @ 144064  76*128*2 = 19456
   xp  @ 163520  76*4     =   304
   total 163824 <= 163840 */
#define OFF_H0 0
#define OFF_H1 19456
#define OFF_A  59584
#define OFF_B  101824
#define OFF_UB 144064
#define OFF_XP 163520
#define LDS_BYTES 163824

// Weights + Chebyshev block-diag fragments in device-global (L2-resident).
__device__ unsigned short g_wall[WTOT];
/* g_sbf: MFMA A-fragments of Sb1 (frags 0..8) and Sb2 (frags 9..17),
   fragment-major [frag][lane][8] so a wave's load is 1 KB contiguous. */
__device__ unsigned short g_sbf[2*9*512];

typedef __attribute__((ext_vector_type(8))) short  bf16x8;
typedef __attribute__((ext_vector_type(4))) float  f32x4;

__device__ __forceinline__ unsigned short f2bf(float v) {
    __hip_bfloat16 b = __float2bfloat16(v);
    return *reinterpret_cast<unsigned short*>(&b);
}
__device__ __forceinline__ float bf2f(unsigned short u) {
    unsigned int x = ((unsigned int)u) << 16;
    return __uint_as_float(x);
}
__device__ __forceinline__ float hload(const unsigned short* p) { return bf2f(*p); }
__device__ __forceinline__ float hload(const float* p)          { return *p; }
__device__ __forceinline__ void  hstore(unsigned short* p, float v) { *p = f2bf(v); }
__device__ __forceinline__ void  hstore(float* p, float v)          { *p = v; }

// ---------------------------------------------------------------------------
// Setup 1: weight reorder/transpose into g_wall.
// Layer-0 (l0=1) K layout is [h(0..127) | x(128) | pad] so staging vectorizes.
// ---------------------------------------------------------------------------
__global__ __launch_bounds__(256) void wconv_kernel(
    const float* __restrict__ W, int F, int O, int KP, int off, int l0)
{
    int idx = blockIdx.x*256 + threadIdx.x;
    int total = 3*O*KP;
    if (idx >= total) return;
    int j   = idx / (O*KP);
    int r   = idx - j*(O*KP);
    int col = r / KP;
    int k   = r - col*KP;
    int src;
    if (l0) src = (k < HH) ? k+1 : ((k == HH) ? 0 : -1);
    else    src = (k < F) ? k : -1;
    float v = (src >= 0) ? W[(size_t)(j*F + src)*O + col] : 0.f;
    g_wall[off + idx] = f2bf(v);
}

// ---------------------------------------------------------------------------
// Setup 2: Sb fragments.  Sb1 = blockdiag(S) (80x96, zero-padded),
// Sb2 = blockdiag(2*S^2 - I).  Non-zero 16x32 fragment tiles (mt,ks):
//   zmt = {0,1,1,2,2,3,3,4,4}, zks = {0,0,1,0,1,1,2,1,2}
// Fragment layout matches mfma_16x16x32 A-operand:
//   lane l, elem e -> Sb[zmt*16 + (l&15)][zks*32 + (l>>4)*8 + e]
// ---------------------------------------------------------------------------
__global__ __launch_bounds__(256) void sbf_kernel(const float* __restrict__ S)
{
    __shared__ float sS[NN*NN], sS2[NN*NN];
    int tid = threadIdx.x;
    for (int i = tid; i < NN*NN; i += 256) sS[i] = S[i];
    __syncthreads();
    for (int i = tid; i < NN*NN; i += 256) {
        int m = i/NN, n = i - m*NN;
        float a = 0.f;
        for (int k = 0; k < NN; ++k) a += sS[m*NN+k]*sS[k*NN+n];
        sS2[i] = a;
    }
    __syncthreads();
    const int zmt[9] = {0,1,1,2,2,3,3,4,4};
    const int zks[9] = {0,0,1,0,1,1,2,1,2};
    for (int idx = tid; idx < 2*9*512; idx += 256) {
        int mat = idx / (9*512);
        int rem = idx - mat*(9*512);
        int i   = rem >> 9;
        int l   = (rem >> 3) & 63;
        int e   = rem & 7;
        int r   = zmt[i]*16 + (l & 15);
        int k   = zks[i]*32 + (l >> 4)*8 + e;
        float v = 0.f;
        if (r < MR) {
            int b = r / NN, m = r - b*NN;
            int k0 = b*NN;
            if (k >= k0 && k < k0 + NN) {
                int n = k - k0;
                v = (mat == 0) ? sS[m*NN+n]
                               : (2.f*sS2[m*NN+n] - ((m==n)?1.f:0.f));
            }
        }
        g_sbf[idx] = f2bf(v);
    }
}

// ---------------------------------------------------------------------------
// GEMM helper: one weight segment with depth-2 ring prefetch.
// ---------------------------------------------------------------------------
template<int KS, int NTC>
__device__ __forceinline__ void mma_ring(f32x4 (&acc)[5][NTC],
    const unsigned short* __restrict__ Wj, const unsigned short* __restrict__ Ab,
    int r16, int quad, int sgo)
{
    const unsigned short* wp[NTC];
    #pragma unroll
    for (int nt = 0; nt < NTC; ++nt)
        wp[nt] = Wj + (size_t)(sgo + nt*16 + r16)*(KS*32) + quad*8;
    bf16x8 ring[2][NTC];
    #pragma unroll
    for (int nt = 0; nt < NTC; ++nt) {
        ring[0][nt] = *(const bf16x8*)(wp[nt]);
        if (KS > 1) ring[1][nt] = *(const bf16x8*)(wp[nt] + 32);
    }
    #pragma unroll
    for (int ks = 0; ks < KS; ++ks) {
        bf16x8 cur[NTC];
        #pragma unroll
        for (int nt = 0; nt < NTC; ++nt) cur[nt] = ring[ks & 1][nt];
        if (ks + 2 < KS) {
            #pragma unroll
            for (int nt = 0; nt < NTC; ++nt)
                ring[ks & 1][nt] = *(const bf16x8*)(wp[nt] + (ks + 2)*32);
        }
        #pragma unroll
        for (int mt = 0; mt < 5; ++mt) {
            bf16x8 af = *(const bf16x8*)&Ab[(mt*16 + r16)*SAS + ks*32 + quad*8];
            #pragma unroll
            for (int nt = 0; nt < NTC; ++nt)
                acc[mt][nt] = __builtin_amdgcn_mfma_f32_16x16x32_bf16(
                    af, cur[nt], acc[mt][nt], 0, 0, 0);
        }
    }
}

// ---------------------------------------------------------------------------
// One gconv phase, input-side diffusion:
//   Z1 = Sb1 @ X -> Zb;  Z2 = Sb2 @ X -> X (in place, after barrier B1)
//   acc = X@W0 + Z1@W1 + Z2@W2
// GATE epilogue writes r*h into Zb (next phase's X) + u into ub.
// CAND epilogue updates hL.
// ---------------------------------------------------------------------------
template<int KS, int NTC, bool GATE, int XW, int DCOLS, typename HT, int HSTR>
__device__ __forceinline__ void gconv_phase(
    const unsigned short* __restrict__ BT, const float* __restrict__ bias,
    HT* __restrict__ hL,
    unsigned short* __restrict__ Xb, unsigned short* __restrict__ Zb,
    unsigned short* __restrict__ ub,
    int lane, int w)
{
    constexpr int OC = NTC*128;
    constexpr int KP = KS*32;
    const int r16 = lane & 15, quad = lane >> 4;
    const int sgo = w*(NTC*16);
    const int c0  = w*32;                 /* diffusion col slice */
    const bool dif = (c0 < DCOLS);        /* wave-uniform */

    constexpr int zmt[9] = {0,1,1,2,2,3,3,4,4};
    constexpr int zks[9] = {0,0,1,0,1,1,2,1,2};

    f32x4 z2a[5][2];
    if (dif) {
        /* B fragments for BOTH nt slices: columns of X gathered element-wise;
           rows >= 76 multiply zero Sb columns (values only need finite) */
        bf16x8 Bg[3][2];
        #pragma unroll
        for (int kd = 0; kd < 3; ++kd)
            #pragma unroll
            for (int nt = 0; nt < 2; ++nt) {
                bf16x8 v;
                #pragma unroll
                for (int e = 0; e < 8; ++e)
                    v[e] = (short)Xb[(kd*32 + quad*8 + e)*SAS + c0 + nt*16 + r16];
                Bg[kd][nt] = v;
            }
        f32x4 z1a[5][2];
        #pragma unroll
        for (int mt = 0; mt < 5; ++mt)
            #pragma unroll
            for (int nt = 0; nt < 2; ++nt) {
                z1a[mt][nt] = (f32x4)0.f; z2a[mt][nt] = (f32x4)0.f;
            }
        /* Sb fragment ring, shared across both nt (1KB coalesced wave loads) */
        const unsigned short* s1p = g_sbf + (size_t)lane*8;
        const unsigned short* s2p = g_sbf + 9*512 + (size_t)lane*8;
        bf16x8 s1r[2], s2r[2];
        s1r[0] = *(const bf16x8*)(s1p);
        s2r[0] = *(const bf16x8*)(s2p);
        s1r[1] = *(const bf16x8*)(s1p + 512);
        s2r[1] = *(const bf16x8*)(s2p + 512);
        #pragma unroll
        for (int i = 0; i < 9; ++i) {
            bf16x8 c1 = s1r[i & 1], c2 = s2r[i & 1];
            if (i + 2 < 9) {
                s1r[i & 1] = *(const bf16x8*)(s1p + (i + 2)*512);
                s2r[i & 1] = *(const bf16x8*)(s2p + (i + 2)*512);
            }
            #pragma unroll
            for (int nt = 0; nt < 2; ++nt) {
                z1a[zmt[i]][nt] = __builtin_amdgcn_mfma_f32_16x16x32_bf16(
                    c1, Bg[zks[i]][nt], z1a[zmt[i]][nt], 0, 0, 0);
                z2a[zmt[i]][nt] = __builtin_amdgcn_mfma_f32_16x16x32_bf16(
                    c2, Bg[zks[i]][nt], z2a[zmt[i]][nt], 0, 0, 0);
            }
        }
        /* Z1 -> Zb (pad rows/cols are exact zeros) */
        #pragma unroll
        for (int mt = 0; mt < 5; ++mt)
            #pragma unroll
            for (int nt = 0; nt < 2; ++nt)
                #pragma unroll
                for (int reg = 0; reg < 4; ++reg)
                    Zb[(mt*16 + quad*4 + reg)*SAS + c0 + nt*16 + r16] =
                        f2bf(z1a[mt][nt][reg]);
    }

    f32x4 acc[5][NTC];
    #pragma unroll
    for (int mt = 0; mt < 5; ++mt)
        #pragma unroll
        for (int nt = 0; nt < NTC; ++nt) acc[mt][nt] = (f32x4)0.f;

    /* j = 0 : reads original X */
    mma_ring<KS,NTC>(acc, BT, Xb, r16, quad, sgo);
    __syncthreads();   /* B1: all X reads + Z1 writes complete */
    if (dif) {
        /* Z2 overwrites X in place (disjoint col slices per wave) */
        #pragma unroll
        for (int nt = 0; nt < 2; ++nt)
            #pragma unroll
            for (int mt = 0; mt < 5; ++mt)
                #pragma unroll
                for (int reg = 0; reg < 4; ++reg)
                    Xb[(mt*16 + quad*4 + reg)*SAS + c0 + nt*16 + r16] =
                        f2bf(z2a[mt][nt][reg]);
    }
    /* j = 1 : reads Z1 */
    mma_ring<KS,NTC>(acc, BT + (size_t)OC*KP, Zb, r16, quad, sgo);
    __syncthreads();   /* B2: Z2 writes complete */
    /* j = 2 : reads X (= Z2) */
    mma_ring<KS,NTC>(acc, BT + (size_t)2*OC*KP, Xb, r16, quad, sgo);

    float bv[NTC];
    #pragma unroll
    for (int nt = 0; nt < NTC; ++nt) bv[nt] = bias[sgo + nt*16 + r16];

    /* epilogue: acc rows are b*19+m directly */
    #pragma unroll
    for (int mt = 0; mt < 5; ++mt)
        #pragma unroll
        for (int reg = 0; reg < 4; ++reg) {
            int gm = mt*16 + quad*4 + reg;
            if (gm < MR) {
                #pragma unroll
                for (int nt = 0; nt < NTC; ++nt) {
                    int o = sgo + nt*16 + r16;
                    float v = acc[mt][nt][reg] + bv[nt];
                    if (GATE) {
                        float sg_ = 1.f/(1.f + __expf(-v));
                        if (o < HH)
                            Zb[gm*SAS + XW + o] = f2bf(sg_ * hload(&hL[gm*HSTR + o]));
                        else
                            ub[gm*UBS + (o - HH)] = f2bf(sg_);
                    } else {
                        float c  = 2.f/(1.f + __expf(-2.f*v)) - 1.f;
                        float u  = bf2f(ub[gm*UBS + o]);
                        float ho = hload(&hL[gm*HSTR + o]);
                        hstore(&hL[gm*HSTR + o], u*ho + (1.f - u)*c);
                    }
                }
            }
        }
}

// ---------------------------------------------------------------------------
// Persistent kernel: 256 blocks x 512 threads.
// __launch_bounds__(512, 2): 2 waves/EU minimum (= our LDS-pinned occupancy)
// -> 256-reg unified budget per wave, no spills.
// ---------------------------------------------------------------------------
__global__ __launch_bounds__(NT, 2) void dcgru_persistent(
    const float* __restrict__ ihs,
    const float* __restrict__ bg0, const float* __restrict__ bc0,
    const float* __restrict__ bg1, const float* __restrict__ bc1,
    const float* __restrict__ Wp, const float* __restrict__ bp,
    float* __restrict__ out)
{
    extern __shared__ char smem[];
    unsigned short* h0 = (unsigned short*)(smem + OFF_H0);
    float*          h1 = (float*)(smem + OFF_H1);
    unsigned short* A  = (unsigned short*)(smem + OFF_A);
    unsigned short* Bb = (unsigned short*)(smem + OFF_B);
    unsigned short* ub = (unsigned short*)(smem + OFF_UB);
    float*       xprev = (float*)(smem + OFF_XP);

    const int tid  = threadIdx.x;
    const int lane = tid & 63;
    const int w    = tid >> 6;          /* 0..7 */
    const int bb   = blockIdx.x * NB;

    const unsigned short* BTg0 = g_wall + OFF_G0;
    const unsigned short* BTc0 = g_wall + OFF_C0;
    const unsigned short* BTg1 = g_wall + OFF_G1;
    const unsigned short* BTc1 = g_wall + OFF_C1;

    for (int i = tid; i < MR*HH; i += NT) {
        h0[i] = f2bf(ihs[(size_t)bb*2432 + i]);
        h1[(i >> 7)*H1S + (i & 127)] = ihs[(size_t)(BATCH + bb)*2432 + i];
    }
    for (int i = tid; i < MR; i += NT) xprev[i] = 0.f;
    /* zero both A/Z buffers fully (pad rows + never-staged cols stay finite) */
    for (int i = tid; i < 80*SAS/8; i += NT) {
        ((bf16x8*)A)[i]  = (bf16x8)(short)0;
        ((bf16x8*)Bb)[i] = (bf16x8)(short)0;
    }
    const float wp0 = Wp[lane], wp1 = Wp[64 + lane], bpv = bp[0];
    __syncthreads();

    for (int t = 0; t < SEQ; ++t) {
        // ---- stage layer 0: A = [h0 | x | 0]  (K = 160) ----
        for (int i = tid; i < MR*16; i += NT) {
            int row = i >> 4, ch = i & 15;
            *(bf16x8*)&A[row*SAS + ch*8] =
                *(const bf16x8*)&h0[row*H0S + ch*8];
        }
        for (int i = tid; i < MR*32; i += NT) {
            int row = i >> 5, c = i & 31;
            A[row*SAS + HH + c] = (c == 0) ? f2bf(xprev[row]) : (unsigned short)0;
        }
        __syncthreads();
        gconv_phase<5,2,true ,0,160,unsigned short,H0S>(BTg0, bg0, h0, A, Bb, ub, lane, w);
        /* restore x col into cand's X (gate epilogue wrote r*h0 at cols 0..127;
           cols 129..159 of Bb are exact zeros from the Z1 pass) */
        for (int i = tid; i < MR; i += NT) Bb[i*SAS + HH] = f2bf(xprev[i]);
        __syncthreads();
        gconv_phase<5,1,false,0,160,unsigned short,H0S>(BTc0, bc0, h0, Bb, A, ub, lane, w);
        __syncthreads();

        // ---- stage layer 1: A = [h0 | h1]  (K = 256) ----
        for (int i = tid; i < MR*16; i += NT) {
            int row = i >> 4, ch = i & 15;
            *(bf16x8*)&A[row*SAS + ch*8] =
                *(const bf16x8*)&h0[row*H0S + ch*8];
        }
        for (int i = tid; i < MR*16; i += NT) {
            int row = i >> 4, ch = i & 15;
            const float* hp = &h1[row*H1S + ch*8];
            f32x4 x0 = *(const f32x4*)hp;
            f32x4 x1 = *(const f32x4*)(hp + 4);
            bf16x8 v;
            v[0] = (short)f2bf(x0[0]); v[1] = (short)f2bf(x0[1]);
            v[2] = (short)f2bf(x0[2]); v[3] = (short)f2bf(x0[3]);
            v[4] = (short)f2bf(x1[0]); v[5] = (short)f2bf(x1[1]);
            v[6] = (short)f2bf(x1[2]); v[7] = (short)f2bf(x1[3]);
            *(bf16x8*)&A[row*SAS + HH + ch*8] = v;
        }
        __syncthreads();
        gconv_phase<8,2,true ,HH,256,float,H1S>(BTg1, bg1, h1, A, Bb, ub, lane, w);
        /* restore h0 half of cand's X (gate epilogue wrote r*h1 at cols 128..255) */
        for (int i = tid; i < MR*16; i += NT) {
            int row = i >> 4, ch = i & 15;
            *(bf16x8*)&Bb[row*SAS + ch*8] =
                *(const bf16x8*)&h0[row*H0S + ch*8];
        }
        __syncthreads();
        gconv_phase<8,1,false,HH,256,float,H1S>(BTc1, bc1, h1, Bb, A, ub, lane, w);
        __syncthreads();

        // ---- projection: wave w -> batch w>>1, half the nodes ----
        {
            int b  = w >> 1;
            int n0 = (w & 1) ? 10 : 0;
            int n1 = (w & 1) ? 19 : 10;
            for (int n = n0; n < n1; ++n) {
                int row = b*NN + n;
                float s = h1[row*H1S + lane]*wp0 + h1[row*H1S + 64 + lane]*wp1;
                #pragma unroll
                for (int off = 32; off; off >>= 1) s += __shfl_down(s, off, 64);
                if (lane == 0) {
                    float v = s + bpv;
                    out[((size_t)t*BATCH + bb + b)*NN + n] = v;
                    xprev[row] = v;
                }
            }
        }
        __syncthreads();
    }
}

// ---------------------------------------------------------------------------
extern "C" void kernel_launch(void* const* d_in, const int* in_sizes, int n_in,
                              void* d_out, int out_size, void* d_ws, size_t ws_size,
                              hipStream_t stream) {
    const float* ihs = (const float*)d_in[1];
    const float* S   = (const float*)d_in[2];
    const float* Wg0 = (const float*)d_in[3];
    const float* bg0 = (const float*)d_in[4];
    const float* Wc0 = (const float*)d_in[5];
    const float* bc0 = (const float*)d_in[6];
    const float* Wg1 = (const float*)d_in[7];
    const float* bg1 = (const float*)d_in[8];
    const float* Wc1 = (const float*)d_in[9];
    const float* bc1 = (const float*)d_in[10];
    const float* Wp  = (const float*)d_in[11];
    const float* bp  = (const float*)d_in[12];
    float* out = (float*)d_out;

    sbf_kernel<<<1, 256, 0, stream>>>(S);
    wconv_kernel<<<(3*256*160+255)/256, 256, 0, stream>>>(Wg0, 129, 256, 160, OFF_G0, 1);
    wconv_kernel<<<(3*128*160+255)/256, 256, 0, stream>>>(Wc0, 129, 128, 160, OFF_C0, 1);
    wconv_kernel<<<(3*256*256+255)/256, 256, 0, stream>>>(Wg1, 256, 256, 256, OFF_G1, 0);
    wconv_kernel<<<(3*128*256+255)/256, 256, 0, stream>>>(Wc1, 256, 128, 256, OFF_C1, 0);

    hipFuncSetAttribute((const void*)dcgru_persistent,
                        hipFuncAttributeMaxDynamicSharedMemorySize, LDS_BYTES);

    dcgru_persistent<<<NBLK, NT, LDS_BYTES, stream>>>(
        ihs, bg0, bc0, bg1, bc1, Wp, bp, out);
}

// Round 5
// 2610.215 us; speedup vs baseline: 1.4064x; 1.4064x over previous
//
#include <hip/hip_runtime.h>
#include <hip/hip_bf16.h>
#include <math.h>

#define SEQ   32
#define BATCH 1024
#define NN    19
#define HH    128
#define NB    4            /* batch elements per block */
#define MR    (NB*NN)      /* 76 rows per block */
#define SAS   264          /* sA row stride (bf16): 528 B = 16B-aligned, 4-bank shift */
#define H0S   128          /* h0 row stride (bf16) */
#define H1S   132          /* h1 row stride (f32): 528 B, 16B-aligned */
#define UBS   128          /* ub row stride (bf16) */
#define NBLK  (BATCH/NB)   /* 256 blocks, 1 per CU */
#define NT    512          /* 8 waves, 2 per SIMD */
#define UST_S 40           /* Ust col stride (elems): 80 B = 16B-aligned, 20-bank shift */

#define OFF_G0 0
#define OFF_C0 122880
#define OFF_G1 184320
#define OFF_C1 380928
#define WTOT   479232      /* total weight elems (bf16) */

/* LDS map:
   h0   @      0  76*128*2 = 19456
   h1   @  19456  76*132*4 = 40128   (end  59584)
   sA   @  59584  80*264*2 = 42240   (end 101824; rows 76-79 stay zero)
   ub   @ 101824  76*128*2 = 19456   (end 121280)
   sbf  @ 121280  2*9*512*2= 18432   (end 139712; Tblk MFMA A-frags)
   Ust  @ 139712  8*32*40*2= 20480   (end 160192; per-wave mixing scratch)
   xp   @ 160192  76*4     =   304   (end 160496)  */
#define OFF_H0  0
#define OFF_H1  19456
#define OFF_SA  59584
#define OFF_UB  101824
#define OFF_SBF 121280
#define OFF_UST 139712
#define OFF_XP  160192
#define LDS_BYTES 160496

// Weights + Chebyshev block-diag fragments in device-global (L2-resident).
__device__ unsigned short g_wall[WTOT];
/* g_sbf: MFMA A-fragments of Tblk1 = blockdiag(S) (frags 0..8) and
   Tblk2 = blockdiag(2S^2-I) (frags 9..17), fragment-major [frag][lane][8],
   frag order grouped by kt: kt0:(mt 0,1,2) kt1:(mt 1,2,3,4) kt2:(mt 3,4). */
__device__ unsigned short g_sbf[2*9*512];

typedef __attribute__((ext_vector_type(8))) short  bf16x8;
typedef __attribute__((ext_vector_type(4))) short  bf16x4;
typedef __attribute__((ext_vector_type(4))) float  f32x4;

__device__ __forceinline__ unsigned short f2bf(float v) {
    __hip_bfloat16 b = __float2bfloat16(v);
    return *reinterpret_cast<unsigned short*>(&b);
}
__device__ __forceinline__ float bf2f(unsigned short u) {
    unsigned int x = ((unsigned int)u) << 16;
    return __uint_as_float(x);
}
__device__ __forceinline__ float hload(const unsigned short* p) { return bf2f(*p); }
__device__ __forceinline__ float hload(const float* p)          { return *p; }
__device__ __forceinline__ void  hstore(unsigned short* p, float v) { *p = f2bf(v); }
__device__ __forceinline__ void  hstore(float* p, float v)          { *p = v; }

// ---------------------------------------------------------------------------
// Setup 1: weight reorder/transpose into g_wall.
// Layer-0 (l0=1) K layout is [h(0..127) | x(128) | pad] so staging vectorizes.
// ---------------------------------------------------------------------------
__global__ __launch_bounds__(256) void wconv_kernel(
    const float* __restrict__ W, int F, int O, int KP, int off, int l0)
{
    int idx = blockIdx.x*256 + threadIdx.x;
    int total = 3*O*KP;
    if (idx >= total) return;
    int j   = idx / (O*KP);
    int r   = idx - j*(O*KP);
    int col = r / KP;
    int k   = r - col*KP;
    int src;
    if (l0) src = (k < HH) ? k+1 : ((k == HH) ? 0 : -1);
    else    src = (k < F) ? k : -1;
    float v = (src >= 0) ? W[(size_t)(j*F + src)*O + col] : 0.f;
    g_wall[off + idx] = f2bf(v);
}

// ---------------------------------------------------------------------------
// Setup 2: Tblk fragments (80x96 block-diag, zero-padded).
// A-frag layout (mfma_16x16x32): lane l, elem e ->
//   Tblk[fmt*16 + (l&15)][fkt*32 + (l>>4)*8 + e]
// ---------------------------------------------------------------------------
__global__ __launch_bounds__(256) void sbf_kernel(const float* __restrict__ S)
{
    __shared__ float sS[NN*NN], sS2[NN*NN];
    int tid = threadIdx.x;
    for (int i = tid; i < NN*NN; i += 256) sS[i] = S[i];
    __syncthreads();
    for (int i = tid; i < NN*NN; i += 256) {
        int m = i/NN, n = i - m*NN;
        float a = 0.f;
        for (int k = 0; k < NN; ++k) a += sS[m*NN+k]*sS[k*NN+n];
        sS2[i] = a;
    }
    __syncthreads();
    const int fmt[9] = {0,1,2, 1,2,3,4, 3,4};
    const int fkt[9] = {0,0,0, 1,1,1,1, 2,2};
    for (int idx = tid; idx < 2*9*512; idx += 256) {
        int mat = idx / 4608;
        int rem = idx - mat*4608;
        int i   = rem >> 9;
        int l   = (rem >> 3) & 63;
        int e   = rem & 7;
        int r   = fmt[i]*16 + (l & 15);
        int k   = fkt[i]*32 + (l >> 4)*8 + e;
        float v = 0.f;
        if (r < MR) {
            int b = r / NN, m = r - b*NN;
            int k0 = b*NN;
            if (k >= k0 && k < k0 + NN) {
                int n = k - k0;
                v = (mat == 0) ? sS[m*NN+n]
                               : (2.f*sS2[m*NN+n] - ((m==n)?1.f:0.f));
            }
        }
        g_sbf[idx] = f2bf(v);
    }
}

// ---------------------------------------------------------------------------
// One gconv phase (output-side mixing via per-wave LDS scratch):
//   acc[j] = X @ Wj  (fused 3-segment K-loop, depth-2 weight ring, r0-proven)
//   Y = acc[0] + Tblk1@acc[1] + Tblk2@acc[2]:
//     per kt-tile, stage acc[j] col-major into private Ust (b64 writes),
//     read B-frags back as aligned b128, MFMA against Tblk A-frags (sbf).
//   No cross-wave sharing -> no barriers in the mixing.
// GATE epilogue: r -> sA cols [XW,XW+128), u -> ub.  CAND: h update.
// ---------------------------------------------------------------------------
template<int KS, int NTC, bool GATE, int XW, typename HT, int HSTR>
__device__ __forceinline__ void gconv_phase(
    const unsigned short* __restrict__ BT, const float* __restrict__ bias,
    HT* __restrict__ hL,
    unsigned short* __restrict__ sA, unsigned short* __restrict__ ub,
    const unsigned short* __restrict__ sbf, unsigned short* __restrict__ Ust,
    int lane, int w)
{
    constexpr int OC = NTC*128;
    constexpr int KP = KS*32;
    const int r16 = lane & 15, quad = lane >> 4;
    const int sgo = w*(NTC*16);

    const unsigned short* wb[3][NTC];
    #pragma unroll
    for (int j = 0; j < 3; ++j)
        #pragma unroll
        for (int nt = 0; nt < NTC; ++nt)
            wb[j][nt] = BT + (size_t)(j*OC + sgo + nt*16 + r16)*KP + quad*8;

    f32x4 acc[3][5][NTC];
    #pragma unroll
    for (int j = 0; j < 3; ++j)
        #pragma unroll
        for (int mt = 0; mt < 5; ++mt)
            #pragma unroll
            for (int nt = 0; nt < NTC; ++nt) acc[j][mt][nt] = (f32x4)0.f;

    /* fused K-loop, depth-2 weight ring (af read once per j-triple) */
    bf16x8 ring[2][3][NTC];
    #pragma unroll
    for (int j = 0; j < 3; ++j)
        #pragma unroll
        for (int nt = 0; nt < NTC; ++nt) {
            ring[0][j][nt] = *(const bf16x8*)(wb[j][nt]);
            if (KS > 1) ring[1][j][nt] = *(const bf16x8*)(wb[j][nt] + 32);
        }
    #pragma unroll
    for (int ks = 0; ks < KS; ++ks) {
        bf16x8 bcur[3][NTC];
        #pragma unroll
        for (int j = 0; j < 3; ++j)
            #pragma unroll
            for (int nt = 0; nt < NTC; ++nt) bcur[j][nt] = ring[ks & 1][j][nt];
        if (ks + 2 < KS) {
            #pragma unroll
            for (int j = 0; j < 3; ++j)
                #pragma unroll
                for (int nt = 0; nt < NTC; ++nt)
                    ring[ks & 1][j][nt] =
                        *(const bf16x8*)(wb[j][nt] + (ks + 2)*32);
        }
        #pragma unroll
        for (int mt = 0; mt < 5; ++mt) {
            bf16x8 af = *(const bf16x8*)&sA[(mt*16 + r16)*SAS + ks*32 + quad*8];
            #pragma unroll
            for (int j = 0; j < 3; ++j)
                #pragma unroll
                for (int nt = 0; nt < NTC; ++nt)
                    acc[j][mt][nt] = __builtin_amdgcn_mfma_f32_16x16x32_bf16(
                        af, bcur[j][nt], acc[j][mt][nt], 0, 0, 0);
        }
    }

    /* ---- output-side mixing: acc[0] += Tblk_j @ acc[j], j = 1,2 ----
       Ust[col][r]: col = wave-local out col (nt*16+r16), r = U row in kt tile.
       C-layout: acc[j][mt][nt][reg] = U[mt*16+quad*4+reg][sgo+nt*16+r16],
       so the reg-quad is contiguous in r -> one b64 write per (mt,nt). */
    constexpr int ktCnt[3]   = {3,4,2};
    constexpr int ktMT[3][4] = {{0,1,2,0},{1,2,3,4},{3,4,0,0}};
    constexpr int ktF0[3]    = {0,3,7};
    #pragma unroll
    for (int j = 1; j <= 2; ++j) {
        #pragma unroll
        for (int kt = 0; kt < 3; ++kt) {
            if (kt == 2) {
                /* U rows 80..95 (scratch rows 16..31, dirtied by kt=1) must be
                   exact zero: they multiply Tblk cols 80..95 which are zero,
                   but 0 * garbage-NaN would poison the accumulator. */
                int zc = lane & 31, zh = lane >> 5;
                *(bf16x8*)&Ust[zc*UST_S + 16 + zh*8] = (bf16x8)(short)0;
            }
            #pragma unroll
            for (int mtk = 0; mtk < 2; ++mtk) {
                constexpr int dummy = 0; (void)dummy;
                int mt = kt*2 + mtk;
                if (kt*2 + mtk < 5) {
                    #pragma unroll
                    for (int nt = 0; nt < NTC; ++nt) {
                        bf16x4 pv;
                        pv[0] = (short)f2bf(acc[j][kt*2+mtk][nt][0]);
                        pv[1] = (short)f2bf(acc[j][kt*2+mtk][nt][1]);
                        pv[2] = (short)f2bf(acc[j][kt*2+mtk][nt][2]);
                        pv[3] = (short)f2bf(acc[j][kt*2+mtk][nt][3]);
                        *(bf16x4*)&Ust[(nt*16 + r16)*UST_S + mtk*16 + quad*4] = pv;
                    }
                }
                (void)mt;
            }
            bf16x8 Bf[NTC];
            #pragma unroll
            for (int nt = 0; nt < NTC; ++nt)
                Bf[nt] = *(const bf16x8*)&Ust[(nt*16 + r16)*UST_S + quad*8];
            #pragma unroll
            for (int q = 0; q < ktCnt[kt]; ++q) {
                const int mt = ktMT[kt][q];
                bf16x8 af = *(const bf16x8*)
                    &sbf[((j-1)*9 + ktF0[kt] + q)*512 + lane*8];
                #pragma unroll
                for (int nt = 0; nt < NTC; ++nt)
                    acc[0][mt][nt] = __builtin_amdgcn_mfma_f32_16x16x32_bf16(
                        af, Bf[nt], acc[0][mt][nt], 0, 0, 0);
            }
        }
    }

    float bv[NTC];
    #pragma unroll
    for (int nt = 0; nt < NTC; ++nt) bv[nt] = bias[sgo + nt*16 + r16];

    if (GATE) __syncthreads();   /* all sA reads done before epilogue rewrites */

    #pragma unroll
    for (int mt = 0; mt < 5; ++mt)
        #pragma unroll
        for (int reg = 0; reg < 4; ++reg) {
            int gm = mt*16 + quad*4 + reg;
            if (gm < MR) {
                #pragma unroll
                for (int nt = 0; nt < NTC; ++nt) {
                    int o = sgo + nt*16 + r16;
                    float v = acc[0][mt][nt][reg] + bv[nt];
                    if (GATE) {
                        float sg_ = 1.f/(1.f + __expf(-v));
                        if (o < HH)
                            sA[gm*SAS + XW + o] =
                                f2bf(sg_ * hload(&hL[gm*HSTR + o]));
                        else
                            ub[gm*UBS + (o - HH)] = f2bf(sg_);
                    } else {
                        float c  = 2.f/(1.f + __expf(-2.f*v)) - 1.f;
                        float u  = bf2f(ub[gm*UBS + o]);
                        float ho = hload(&hL[gm*HSTR + o]);
                        hstore(&hL[gm*HSTR + o], u*ho + (1.f - u)*c);
                    }
                }
            }
        }
}

// ---------------------------------------------------------------------------
// Persistent kernel: 256 blocks x 512 threads (8 waves, 2/SIMD).
// ---------------------------------------------------------------------------
__global__ __launch_bounds__(NT, 2) void dcgru_persistent(
    const float* __restrict__ ihs,
    const float* __restrict__ bg0, const float* __restrict__ bc0,
    const float* __restrict__ bg1, const float* __restrict__ bc1,
    const float* __restrict__ Wp, const float* __restrict__ bp,
    float* __restrict__ out)
{
    extern __shared__ char smem[];
    unsigned short* h0  = (unsigned short*)(smem + OFF_H0);
    float*          h1  = (float*)(smem + OFF_H1);
    unsigned short* sA  = (unsigned short*)(smem + OFF_SA);
    unsigned short* ub  = (unsigned short*)(smem + OFF_UB);
    unsigned short* sbf = (unsigned short*)(smem + OFF_SBF);
    float*       xprev  = (float*)(smem + OFF_XP);

    const int tid  = threadIdx.x;
    const int lane = tid & 63;
    const int w    = tid >> 6;          /* 0..7 */
    const int bb   = blockIdx.x * NB;
    unsigned short* Ust = (unsigned short*)(smem + OFF_UST) + w*(32*UST_S);

    const unsigned short* BTg0 = g_wall + OFF_G0;
    const unsigned short* BTc0 = g_wall + OFF_C0;
    const unsigned short* BTg1 = g_wall + OFF_G1;
    const unsigned short* BTc1 = g_wall + OFF_C1;

    for (int i = tid; i < MR*HH; i += NT) {
        h0[i] = f2bf(ihs[(size_t)bb*2432 + i]);
        h1[(i >> 7)*H1S + (i & 127)] = ihs[(size_t)(BATCH + bb)*2432 + i];
    }
    for (int i = tid; i < MR; i += NT) xprev[i] = 0.f;
    /* zero sA fully: pad rows 76-79 + pad cols stay exact zeros forever */
    for (int i = tid; i < 80*SAS/8; i += NT) ((bf16x8*)sA)[i] = (bf16x8)(short)0;
    /* Tblk fragments -> LDS (18 KB, once) */
    for (int i = tid; i < 2*9*512/8; i += NT)
        ((bf16x8*)sbf)[i] = ((const bf16x8*)g_sbf)[i];
    const float wp0 = Wp[lane], wp1 = Wp[64 + lane], bpv = bp[0];
    __syncthreads();

    for (int t = 0; t < SEQ; ++t) {
        // ---- stage layer 0: sA = [h0 | x | 0-pad]  (K = 160) ----
        for (int i = tid; i < MR*16; i += NT) {
            int row = i >> 4, ch = i & 15;
            *(bf16x8*)&sA[row*SAS + ch*8] =
                *(const bf16x8*)&h0[row*H0S + ch*8];
        }
        for (int i = tid; i < MR*4; i += NT) {
            int row = i >> 2, ch = i & 3;
            bf16x8 v = (bf16x8)(short)0;
            if (ch == 0) v[0] = (short)f2bf(xprev[row]);
            *(bf16x8*)&sA[row*SAS + HH + ch*8] = v;
        }
        __syncthreads();
        gconv_phase<5,2,true ,0,unsigned short,H0S>(BTg0, bg0, h0, sA, ub, sbf, Ust, lane, w);
        __syncthreads();
        /* sA now [r*h0 | x | 0] */
        gconv_phase<5,1,false,0,unsigned short,H0S>(BTc0, bc0, h0, sA, ub, sbf, Ust, lane, w);
        __syncthreads();

        // ---- stage layer 1: sA = [h0 | h1]  (K = 256) ----
        for (int i = tid; i < MR*16; i += NT) {
            int row = i >> 4, ch = i & 15;
            *(bf16x8*)&sA[row*SAS + ch*8] =
                *(const bf16x8*)&h0[row*H0S + ch*8];
        }
        for (int i = tid; i < MR*16; i += NT) {
            int row = i >> 4, ch = i & 15;
            const float* hp = &h1[row*H1S + ch*8];
            f32x4 x0 = *(const f32x4*)hp;
            f32x4 x1 = *(const f32x4*)(hp + 4);
            bf16x8 v;
            v[0] = (short)f2bf(x0[0]); v[1] = (short)f2bf(x0[1]);
            v[2] = (short)f2bf(x0[2]); v[3] = (short)f2bf(x0[3]);
            v[4] = (short)f2bf(x1[0]); v[5] = (short)f2bf(x1[1]);
            v[6] = (short)f2bf(x1[2]); v[7] = (short)f2bf(x1[3]);
            *(bf16x8*)&sA[row*SAS + HH + ch*8] = v;
        }
        __syncthreads();
        gconv_phase<8,2,true ,HH,float,H1S>(BTg1, bg1, h1, sA, ub, sbf, Ust, lane, w);
        __syncthreads();
        /* sA now [h0 | r*h1] */
        gconv_phase<8,1,false,HH,float,H1S>(BTc1, bc1, h1, sA, ub, sbf, Ust, lane, w);
        __syncthreads();

        // ---- projection: wave w -> batch w>>1, half the nodes ----
        {
            int b  = w >> 1;
            int n0 = (w & 1) ? 10 : 0;
            int n1 = (w & 1) ? 19 : 10;
            for (int n = n0; n < n1; ++n) {
                int row = b*NN + n;
                float s = h1[row*H1S + lane]*wp0 + h1[row*H1S + 64 + lane]*wp1;
                #pragma unroll
                for (int off = 32; off; off >>= 1) s += __shfl_down(s, off, 64);
                if (lane == 0) {
                    float v = s + bpv;
                    out[((size_t)t*BATCH + bb + b)*NN + n] = v;
                    xprev[row] = v;
                }
            }
        }
        __syncthreads();
    }
}

// ---------------------------------------------------------------------------
extern "C" void kernel_launch(void* const* d_in, const int* in_sizes, int n_in,
                              void* d_out, int out_size, void* d_ws, size_t ws_size,
                              hipStream_t stream) {
    const float* ihs = (const float*)d_in[1];
    const float* S   = (const float*)d_in[2];
    const float* Wg0 = (const float*)d_in[3];
    const float* bg0 = (const float*)d_in[4];
    const float* Wc0 = (const float*)d_in[5];
    const float* bc0 = (const float*)d_in[6];
    const float* Wg1 = (const float*)d_in[7];
    const float* bg1 = (const float*)d_in[8];
    const float* Wc1 = (const float*)d_in[9];
    const float* bc1 = (const float*)d_in[10];
    const float* Wp  = (const float*)d_in[11];
    const float* bp  = (const float*)d_in[12];
    float* out = (float*)d_out;

    sbf_kernel<<<1, 256, 0, stream>>>(S);
    wconv_kernel<<<(3*256*160+255)/256, 256, 0, stream>>>(Wg0, 129, 256, 160, OFF_G0, 1);
    wconv_kernel<<<(3*128*160+255)/256, 256, 0, stream>>>(Wc0, 129, 128, 160, OFF_C0, 1);
    wconv_kernel<<<(3*256*256+255)/256, 256, 0, stream>>>(Wg1, 256, 256, 256, OFF_G1, 0);
    wconv_kernel<<<(3*128*256+255)/256, 256, 0, stream>>>(Wc1, 256, 128, 256, OFF_C1, 0);

    hipFuncSetAttribute((const void*)dcgru_persistent,
                        hipFuncAttributeMaxDynamicSharedMemorySize, LDS_BYTES);

    dcgru_persistent<<<NBLK, NT, LDS_BYTES, stream>>>(
        ihs, bg0, bc0, bg1, bc1, Wp, bp, out);
}